// Round 3
// baseline (825.189 us; speedup 1.0000x reference)
//
#include <hip/hip_runtime.h>
#include <math.h>

// GAT layer, restructured (fp32 throughout):
//   M  = W1n @ align_w (16x64), Mt = W1t @ align_w (16x64), Kt = b1 + (W1n+W1t)@align_b
//   u[b][h] = Kt[h] + Mt[h] @ x_target[b]                 (kernel gat_u, 4 MB ws)
//   e[b,i] = leaky( sum_h w2[h]*relu( u[b,h] + M[h]@x_neigh[b,i] ) + b2 )
//   out[b] = elu( align_w @ (softmax(e) @ x_neigh[b]) + align_b )
// x_neigh (587 MB) read exactly once.
// R3: depth-3 software pipeline over the flattened (b,k) load stream,
// no-max online softmax (|e| << 1 structurally, exp safe), and the final
// matvec done with the same reduce-scatter butterfly from a pos-major LDS
// W layout (conflict-free ds_read_b128, no xw broadcast round-trip).

#define ALPHA 0.2f
static constexpr int Bn = 65536;
static constexpr int Nn = 35;
static constexpr int Cn = 64;
static constexpr int NV4 = Nn * Cn / 4;   // 560 v4f per b

typedef float v2f __attribute__((ext_vector_type(2)));
typedef float v4f __attribute__((ext_vector_type(4)));

#define DPP_XOR1 0xB1   // quad_perm [1,0,3,2]
#define DPP_XOR2 0x4E   // quad_perm [2,3,0,1]
#define DPP_HMIR 0x141  // row_half_mirror = xor7
#define DPP_MIR  0x140  // row_mirror      = xor15

template<int CTRL>
__device__ __forceinline__ float dpp_mov(float x) {
  int r = __builtin_amdgcn_update_dpp(0, __builtin_bit_cast(int, x), CTRL, 0xF, 0xF, true);
  return __builtin_bit_cast(float, r);
}

__device__ __forceinline__ v2f pk_mul(v2f a, v2f b) {
  v2f d; asm("v_pk_mul_f32 %0, %1, %2" : "=v"(d) : "v"(a), "v"(b)); return d;
}
__device__ __forceinline__ v2f pk_fma(v2f a, v2f b, v2f c) {
  v2f d; asm("v_pk_fma_f32 %0, %1, %2, %3" : "=v"(d) : "v"(a), "v"(b), "v"(c)); return d;
}
__device__ __forceinline__ v2f lo2(v4f x) { return __builtin_shufflevector(x, x, 0, 1); }
__device__ __forceinline__ v2f hi2(v4f x) { return __builtin_shufflevector(x, x, 2, 3); }

// Storage-order permutation making the butterfly selection-free (verified R2):
// lane m stores at position pos the partial for h = perm_h(pos,m); after the
// 4 DPP stages lane m holds the full 16-lane sum for h = m.
__device__ __forceinline__ int perm_h(int pos, int m) {
  int p3 = (pos >> 3) & 1;
  int e  = ((pos >> 2) ^ (pos >> 3)) & 1;
  return (pos ^ m) ^ (e ? 3 : 0) ^ (p3 ? 4 : 0);
}

// selection-free sum reduce-scatter over each 16-lane DPP row
__device__ __forceinline__ float reduce_scatter16(const float p[16]) {
  float q[8];
#pragma unroll
  for (int j = 0; j < 8; ++j) q[j] = p[2*j] + dpp_mov<DPP_XOR1>(p[2*j+1]);
  float r[4];
#pragma unroll
  for (int j = 0; j < 4; ++j) r[j] = q[2*j] + dpp_mov<DPP_XOR2>(q[2*j+1]);
  float s[2];
#pragma unroll
  for (int j = 0; j < 2; ++j) s[j] = r[2*j] + dpp_mov<DPP_HMIR>(r[2*j+1]);
  return s[0] + dpp_mov<DPP_MIR>(s[1]);
}

__device__ __forceinline__ float row_allreduce_add(float x) {
  x += dpp_mov<DPP_XOR1>(x);
  x += dpp_mov<DPP_XOR2>(x);
  x += dpp_mov<DPP_HMIR>(x);
  x += dpp_mov<DPP_MIR>(x);
  return x;
}

// ---- kernel 1a: fold weights.  M[16][64], Mt[16][64], Kt[16] into ws ----
__global__ void gat_prep(const float* __restrict__ align_w, const float* __restrict__ align_b,
                         const float* __restrict__ a1w, const float* __restrict__ a1b,
                         float* __restrict__ wsM, float* __restrict__ wsMt, float* __restrict__ wsKt) {
  int t = blockIdx.x * 256 + threadIdx.x;
  if (t < 1024) {
    int h = t >> 6, c = t & 63;
    float accM = 0.f, accMt = 0.f;
    for (int d = 0; d < 64; ++d) {
      float w = align_w[d * 64 + c];
      accM  += a1w[h * 128 + 64 + d] * w;   // W1n part
      accMt += a1w[h * 128 + d] * w;        // W1t part
    }
    wsM[t] = accM;
    wsMt[t] = accMt;
  }
  if (t < 16) {
    float acc = a1b[t];
    for (int d = 0; d < 64; ++d)
      acc += (a1w[t * 128 + d] + a1w[t * 128 + 64 + d]) * align_b[d];
    wsKt[t] = acc;
  }
}

// ---- kernel 1b: u[b*16+h] = Kt[h] + Mt[h] @ x_target[b]  (h = gt&15) ----
__global__ void gat_u(const float* __restrict__ xt, const float* __restrict__ wsMt,
                      const float* __restrict__ wsKt, float* __restrict__ u_arr) {
  int gt = blockIdx.x * 256 + threadIdx.x;
  int b = gt >> 4, h = gt & 15;
  const v4f* xr = (const v4f*)(xt + (size_t)b * 64);
  const v4f* Mr = (const v4f*)(wsMt + h * 64);
  float acc = wsKt[h];
#pragma unroll
  for (int j = 0; j < 16; ++j) {
    v4f a = Mr[j], x = xr[j];
    acc += a.x * x.x + a.y * x.y + a.z * x.z + a.w * x.w;
  }
  u_arr[gt] = acc;
}

// ---- main fused kernel: one wave per b, depth-3 pipelined load stream ----
template<bool PRECOMP_U, int MINWAVES>
__global__ __launch_bounds__(256, MINWAVES) void gat_main(
    const float* __restrict__ x_target, const float* __restrict__ x_neigh,
    const float* __restrict__ align_w, const float* __restrict__ align_b,
    const float* __restrict__ attn2_w, const float* __restrict__ attn2_b,
    const float* __restrict__ wsM, const float* __restrict__ wsMt,
    const float* __restrict__ wsKt, const float* __restrict__ u_arr,
    float* __restrict__ out, int waves_total) {
  // pos-major permuted align_w: W2[pos][lane] = align_w[g*16+perm_h(pos,m)][4m..4m+3]
  __shared__ v4f W2[16][64];
  int tid = threadIdx.x;
  for (int idx = tid; idx < 1024; idx += 256) {
    int pos = idx >> 6, l = idx & 63, mm = l & 15, gg = l >> 4;
    int row = gg * 16 + perm_h(pos, mm);
    W2[pos][l] = *(const v4f*)(align_w + row * 64 + 4 * mm);
  }
  __syncthreads();

  const int lane = tid & 63, wave = tid >> 6;
  const int m = lane & 15, g = lane >> 4;

  // persistent score weights, permuted storage order
  v2f Mlo[16], Mhi[16];
#pragma unroll
  for (int pos = 0; pos < 16; ++pos) {
    int h = perm_h(pos, m);
    v4f Mv = *(const v4f*)(wsM + h * 64 + 4 * m);
    Mlo[pos] = lo2(Mv); Mhi[pos] = hi2(Mv);
  }
  const float w2r = attn2_w[m];       // lane m ends butterfly with h=m
  const float b2r = attn2_b[0];
  const float biasr = align_b[lane];

  v2f Mtlo[16], Mthi[16];
  float Ktr = 0.f;
  if constexpr (!PRECOMP_U) {
#pragma unroll
    for (int pos = 0; pos < 16; ++pos) {
      int h = perm_h(pos, m);
      v4f Mv = *(const v4f*)(wsMt + h * 64 + 4 * m);
      Mtlo[pos] = lo2(Mv); Mthi[pos] = hi2(Mv);
    }
    Ktr = wsKt[m];
  }

  const int stride_b = waves_total;
  int b = blockIdx.x * 4 + wave;
  if (b >= Bn) return;

  const v4f* xv = (const v4f*)x_neigh;
  const size_t LASTV = (size_t)Bn * NV4 - 1;

  const v4f* pc = xv + (size_t)b * NV4 + lane;
  // prefill: (b, k=0..2)
  v4f xq0 = pc[0], xq1 = pc[64], xq2 = pc[128];
  float u_cur = 0.f;
  if constexpr (PRECOMP_U) u_cur = u_arr[(size_t)b * 16 + m];

  for (; b < Bn; b += stride_b) {
    const int bn = b + stride_b;
    const size_t bno = (size_t)(bn < Bn ? bn : Bn - 1) * NV4;
    const v4f* pn = xv + bno + lane;

    if constexpr (!PRECOMP_U) {
      v4f xt4 = *(const v4f*)(x_target + (size_t)b * 64 + 4 * m);
      v2f xtlo = lo2(xt4), xthi = hi2(xt4);
      float up[16];
#pragma unroll
      for (int pos = 0; pos < 16; ++pos) {
        v2f t = pk_mul(Mtlo[pos], xtlo);
        t = pk_fma(Mthi[pos], xthi, t);
        up[pos] = t.x + t.y;
      }
      u_cur = reduce_scatter16(up) + Ktr;
    }

    float s_acc = 0.f;
    v4f xw = {0.f, 0.f, 0.f, 0.f};

    // one (b,k) step: score -> weight -> online accumulate
    auto step = [&](v4f xk, bool mask35) {
      v2f xlo = lo2(xk), xhi = hi2(xk);
      float p[16];
#pragma unroll
      for (int pos = 0; pos < 16; ++pos) {
        v2f t = pk_mul(Mlo[pos], xlo);
        t = pk_fma(Mhi[pos], xhi, t);
        p[pos] = t.x + t.y;
      }
      float P = reduce_scatter16(p);
      float rr = fmaxf(P + u_cur, 0.f) * w2r;
      float esum = row_allreduce_add(rr) + b2r;
      float e = fmaxf(esum, 0.f) + ALPHA * fminf(esum, 0.f);   // leaky_relu
      float w = __expf(e);                                     // no-max: |e|<<1
      if (mask35 && g == 3) w = 0.f;                           // row i=35 absent
      s_acc += w;
      xw.x = fmaf(w, xk.x, xw.x);
      xw.y = fmaf(w, xk.y, xw.y);
      xw.z = fmaf(w, xk.z, xw.z);
      xw.w = fmaf(w, xk.w, xw.w);
    };

    // k-steps; each consumes slot k%3 then refills it with stream pos k+3
    { v4f t = xq0; xq0 = pc[192]; step(t, false); }                 // k=0 -> (b,3)
    { v4f t = xq1; xq1 = pc[256]; step(t, false); }                 // k=1 -> (b,4)
    { v4f t = xq2; xq2 = pc[320]; step(t, false); }                 // k=2 -> (b,5)
    { v4f t = xq0; xq0 = pc[384]; step(t, false); }                 // k=3 -> (b,6)
    { v4f t = xq1; xq1 = pc[448]; step(t, false); }                 // k=4 -> (b,7)
    {
      v4f t = xq2;                                                  // k=5 -> (b,8)
      size_t idx = (size_t)b * NV4 + 512 + lane;                    // lanes>=48 spill
      if (idx > LASTV) idx = LASTV;                                 // into next b (masked)
      xq2 = xv[idx];
      step(t, false);
    }
    float u_nxt = u_cur;
    { v4f t = xq0; xq0 = pn[0];   step(t, false); }                 // k=6 -> (bn,0)
    if constexpr (PRECOMP_U)
      u_nxt = u_arr[(size_t)(bn < Bn ? bn : Bn - 1) * 16 + m];
    { v4f t = xq1; xq1 = pn[64];  step(t, false); }                 // k=7 -> (bn,1)
    { v4f t = xq2; xq2 = pn[128]; step(t, true);  }                 // k=8 -> (bn,2)

    // ---- cross-row (g) combine + normalize ----
    s_acc += __shfl_xor(s_acc, 16); s_acc += __shfl_xor(s_acc, 32);
    xw.x += __shfl_xor(xw.x, 16); xw.x += __shfl_xor(xw.x, 32);
    xw.y += __shfl_xor(xw.y, 16); xw.y += __shfl_xor(xw.y, 32);
    xw.z += __shfl_xor(xw.z, 16); xw.z += __shfl_xor(xw.z, 32);
    xw.w += __shfl_xor(xw.w, 16); xw.w += __shfl_xor(xw.w, 32);
    const float rS = 1.f / s_acc;
    v2f xwlo = { xw.x * rS, xw.y * rS };
    v2f xwhi = { xw.z * rS, xw.w * rS };

    // ---- final matvec via the same butterfly; lane ends with out[lane] ----
    float q[16];
#pragma unroll
    for (int pos = 0; pos < 16; ++pos) {
      v4f Wv = W2[pos][lane];                 // conflict-free ds_read_b128
      v2f t = pk_mul(lo2(Wv), xwlo);
      t = pk_fma(hi2(Wv), xwhi, t);
      q[pos] = t.x + t.y;
    }
    float hp = reduce_scatter16(q) + biasr;
    float res = hp > 0.f ? hp : (__expf(hp) - 1.f);   // elu
    out[(size_t)b * 64 + lane] = res;

    pc = pn;
    u_cur = u_nxt;
  }
}

extern "C" void kernel_launch(void* const* d_in, const int* in_sizes, int n_in,
                              void* d_out, int out_size, void* d_ws, size_t ws_size,
                              hipStream_t stream) {
  const float* x_target = (const float*)d_in[0];
  const float* x_neigh  = (const float*)d_in[1];
  const float* align_w  = (const float*)d_in[2];
  const float* align_b  = (const float*)d_in[3];
  const float* attn1_w  = (const float*)d_in[4];
  const float* attn1_b  = (const float*)d_in[5];
  const float* attn2_w  = (const float*)d_in[6];
  const float* attn2_b  = (const float*)d_in[7];
  float* out = (float*)d_out;

  float* ws = (float*)d_ws;
  float* wsM  = ws;            // 1024 floats
  float* wsMt = ws + 1024;     // 1024 floats
  float* wsKt = ws + 2048;     // 16 floats
  float* u_arr = ws + 2064;    // B*16 floats (4 MB)
  size_t need = (2064 + (size_t)Bn * 16) * sizeof(float);
  bool precomp = ws_size >= need;

  gat_prep<<<4, 256, 0, stream>>>(align_w, align_b, attn1_w, attn1_b, wsM, wsMt, wsKt);

  const int blocks = 2048;
  const int waves_total = blocks * 4;
  if (precomp) {
    gat_u<<<(Bn * 16) / 256, 256, 0, stream>>>(x_target, wsMt, wsKt, u_arr);
    gat_main<true, 3><<<blocks, 256, 0, stream>>>(x_target, x_neigh, align_w, align_b,
                                                  attn2_w, attn2_b, wsM, wsMt, wsKt,
                                                  u_arr, out, waves_total);
  } else {
    gat_main<false, 2><<<blocks, 256, 0, stream>>>(x_target, x_neigh, align_w, align_b,
                                                   attn2_w, attn2_b, wsM, wsMt, wsKt,
                                                   u_arr, out, waves_total);
  }
}

// Round 4
// 821.316 us; speedup vs baseline: 1.0047x; 1.0047x over previous
//
#include <hip/hip_runtime.h>
#include <math.h>

// GAT layer, restructured (fp32 throughout):
//   M  = W1n @ align_w (16x64), Mt = W1t @ align_w (16x64), Kt = b1 + (W1n+W1t)@align_b
//   u[b][h] = Kt[h] + Mt[h] @ x_target[b]                 (kernel gat_u, 4 MB ws)
//   e[b,i] = leaky( sum_h w2[h]*relu( u[b,h] + M[h]@x_neigh[b,i] ) + b2 )
//   out[b] = elu( align_w @ (softmax(e) @ x_neigh[b]) + align_b )
// x_neigh (587 MB) read exactly once.
// R4: __launch_bounds__(256,4) -> 4 waves/SIMD (VGPR<=128; enabled by the
// depth-3 pipeline's small x footprint), v_rcp for 1/S to shorten the
// epilogue serial chain. Butterfly reduce-scatter + no-max softmax verified.

#define ALPHA 0.2f
static constexpr int Bn = 65536;
static constexpr int Nn = 35;
static constexpr int Cn = 64;
static constexpr int NV4 = Nn * Cn / 4;   // 560 v4f per b

typedef float v2f __attribute__((ext_vector_type(2)));
typedef float v4f __attribute__((ext_vector_type(4)));

#define DPP_XOR1 0xB1   // quad_perm [1,0,3,2]
#define DPP_XOR2 0x4E   // quad_perm [2,3,0,1]
#define DPP_HMIR 0x141  // row_half_mirror = xor7
#define DPP_MIR  0x140  // row_mirror      = xor15

template<int CTRL>
__device__ __forceinline__ float dpp_mov(float x) {
  int r = __builtin_amdgcn_update_dpp(0, __builtin_bit_cast(int, x), CTRL, 0xF, 0xF, true);
  return __builtin_bit_cast(float, r);
}

__device__ __forceinline__ v2f pk_mul(v2f a, v2f b) {
  v2f d; asm("v_pk_mul_f32 %0, %1, %2" : "=v"(d) : "v"(a), "v"(b)); return d;
}
__device__ __forceinline__ v2f pk_fma(v2f a, v2f b, v2f c) {
  v2f d; asm("v_pk_fma_f32 %0, %1, %2, %3" : "=v"(d) : "v"(a), "v"(b), "v"(c)); return d;
}
__device__ __forceinline__ v2f lo2(v4f x) { return __builtin_shufflevector(x, x, 0, 1); }
__device__ __forceinline__ v2f hi2(v4f x) { return __builtin_shufflevector(x, x, 2, 3); }

// Storage-order permutation making the butterfly selection-free (verified R2/R3):
// lane m stores at position pos the partial for h = perm_h(pos,m); after the
// 4 DPP stages lane m holds the full 16-lane sum for h = m.
__device__ __forceinline__ int perm_h(int pos, int m) {
  int p3 = (pos >> 3) & 1;
  int e  = ((pos >> 2) ^ (pos >> 3)) & 1;
  return (pos ^ m) ^ (e ? 3 : 0) ^ (p3 ? 4 : 0);
}

// selection-free sum reduce-scatter over each 16-lane DPP row
__device__ __forceinline__ float reduce_scatter16(const float p[16]) {
  float q[8];
#pragma unroll
  for (int j = 0; j < 8; ++j) q[j] = p[2*j] + dpp_mov<DPP_XOR1>(p[2*j+1]);
  float r[4];
#pragma unroll
  for (int j = 0; j < 4; ++j) r[j] = q[2*j] + dpp_mov<DPP_XOR2>(q[2*j+1]);
  float s[2];
#pragma unroll
  for (int j = 0; j < 2; ++j) s[j] = r[2*j] + dpp_mov<DPP_HMIR>(r[2*j+1]);
  return s[0] + dpp_mov<DPP_MIR>(s[1]);
}

__device__ __forceinline__ float row_allreduce_add(float x) {
  x += dpp_mov<DPP_XOR1>(x);
  x += dpp_mov<DPP_XOR2>(x);
  x += dpp_mov<DPP_HMIR>(x);
  x += dpp_mov<DPP_MIR>(x);
  return x;
}

// ---- kernel 1a: fold weights.  M[16][64], Mt[16][64], Kt[16] into ws ----
__global__ void gat_prep(const float* __restrict__ align_w, const float* __restrict__ align_b,
                         const float* __restrict__ a1w, const float* __restrict__ a1b,
                         float* __restrict__ wsM, float* __restrict__ wsMt, float* __restrict__ wsKt) {
  int t = blockIdx.x * 256 + threadIdx.x;
  if (t < 1024) {
    int h = t >> 6, c = t & 63;
    float accM = 0.f, accMt = 0.f;
    for (int d = 0; d < 64; ++d) {
      float w = align_w[d * 64 + c];
      accM  += a1w[h * 128 + 64 + d] * w;   // W1n part
      accMt += a1w[h * 128 + d] * w;        // W1t part
    }
    wsM[t] = accM;
    wsMt[t] = accMt;
  }
  if (t < 16) {
    float acc = a1b[t];
    for (int d = 0; d < 64; ++d)
      acc += (a1w[t * 128 + d] + a1w[t * 128 + 64 + d]) * align_b[d];
    wsKt[t] = acc;
  }
}

// ---- kernel 1b: u[b*16+h] = Kt[h] + Mt[h] @ x_target[b]  (h = gt&15) ----
__global__ void gat_u(const float* __restrict__ xt, const float* __restrict__ wsMt,
                      const float* __restrict__ wsKt, float* __restrict__ u_arr) {
  int gt = blockIdx.x * 256 + threadIdx.x;
  int b = gt >> 4, h = gt & 15;
  const v4f* xr = (const v4f*)(xt + (size_t)b * 64);
  const v4f* Mr = (const v4f*)(wsMt + h * 64);
  float acc = wsKt[h];
#pragma unroll
  for (int j = 0; j < 16; ++j) {
    v4f a = Mr[j], x = xr[j];
    acc += a.x * x.x + a.y * x.y + a.z * x.z + a.w * x.w;
  }
  u_arr[gt] = acc;
}

// ---- main fused kernel: one wave per b, depth-3 pipelined load stream ----
template<bool PRECOMP_U, int MINWAVES>
__global__ __launch_bounds__(256, MINWAVES) void gat_main(
    const float* __restrict__ x_target, const float* __restrict__ x_neigh,
    const float* __restrict__ align_w, const float* __restrict__ align_b,
    const float* __restrict__ attn2_w, const float* __restrict__ attn2_b,
    const float* __restrict__ wsM, const float* __restrict__ wsMt,
    const float* __restrict__ wsKt, const float* __restrict__ u_arr,
    float* __restrict__ out, int waves_total) {
  // pos-major permuted align_w: W2[pos][lane] = align_w[g*16+perm_h(pos,m)][4m..4m+3]
  __shared__ v4f W2[16][64];
  int tid = threadIdx.x;
  for (int idx = tid; idx < 1024; idx += 256) {
    int pos = idx >> 6, l = idx & 63, mm = l & 15, gg = l >> 4;
    int row = gg * 16 + perm_h(pos, mm);
    W2[pos][l] = *(const v4f*)(align_w + row * 64 + 4 * mm);
  }
  __syncthreads();

  const int lane = tid & 63, wave = tid >> 6;
  const int m = lane & 15, g = lane >> 4;

  // persistent score weights, permuted storage order (64 VGPR)
  v2f Mlo[16], Mhi[16];
#pragma unroll
  for (int pos = 0; pos < 16; ++pos) {
    int h = perm_h(pos, m);
    v4f Mv = *(const v4f*)(wsM + h * 64 + 4 * m);
    Mlo[pos] = lo2(Mv); Mhi[pos] = hi2(Mv);
  }
  const float w2r = attn2_w[m];       // lane m ends butterfly with h=m
  const float b2r = attn2_b[0];
  const float biasr = align_b[lane];

  v2f Mtlo[16], Mthi[16];
  float Ktr = 0.f;
  if constexpr (!PRECOMP_U) {
#pragma unroll
    for (int pos = 0; pos < 16; ++pos) {
      int h = perm_h(pos, m);
      v4f Mv = *(const v4f*)(wsMt + h * 64 + 4 * m);
      Mtlo[pos] = lo2(Mv); Mthi[pos] = hi2(Mv);
    }
    Ktr = wsKt[m];
  }

  const int stride_b = waves_total;
  int b = blockIdx.x * 4 + wave;
  if (b >= Bn) return;

  const v4f* xv = (const v4f*)x_neigh;
  const size_t LASTV = (size_t)Bn * NV4 - 1;

  const v4f* pc = xv + (size_t)b * NV4 + lane;
  // prefill: (b, k=0..2)
  v4f xq0 = pc[0], xq1 = pc[64], xq2 = pc[128];
  float u_cur = 0.f;
  if constexpr (PRECOMP_U) u_cur = u_arr[(size_t)b * 16 + m];

  for (; b < Bn; b += stride_b) {
    const int bn = b + stride_b;
    const size_t bno = (size_t)(bn < Bn ? bn : Bn - 1) * NV4;
    const v4f* pn = xv + bno + lane;

    if constexpr (!PRECOMP_U) {
      v4f xt4 = *(const v4f*)(x_target + (size_t)b * 64 + 4 * m);
      v2f xtlo = lo2(xt4), xthi = hi2(xt4);
      float up[16];
#pragma unroll
      for (int pos = 0; pos < 16; ++pos) {
        v2f t = pk_mul(Mtlo[pos], xtlo);
        t = pk_fma(Mthi[pos], xthi, t);
        up[pos] = t.x + t.y;
      }
      u_cur = reduce_scatter16(up) + Ktr;
    }

    float s_acc = 0.f;
    v4f xw = {0.f, 0.f, 0.f, 0.f};

    // one (b,k) step: score -> weight -> online accumulate
    auto step = [&](v4f xk, bool mask35) {
      v2f xlo = lo2(xk), xhi = hi2(xk);
      float p[16];
#pragma unroll
      for (int pos = 0; pos < 16; ++pos) {
        v2f t = pk_mul(Mlo[pos], xlo);
        t = pk_fma(Mhi[pos], xhi, t);
        p[pos] = t.x + t.y;
      }
      float P = reduce_scatter16(p);
      float rr = fmaxf(P + u_cur, 0.f) * w2r;
      float esum = row_allreduce_add(rr) + b2r;
      float e = fmaxf(esum, 0.f) + ALPHA * fminf(esum, 0.f);   // leaky_relu
      float w = __expf(e);                                     // no-max: |e|<<1
      if (mask35 && g == 3) w = 0.f;                           // row i=35 absent
      s_acc += w;
      xw.x = fmaf(w, xk.x, xw.x);
      xw.y = fmaf(w, xk.y, xw.y);
      xw.z = fmaf(w, xk.z, xw.z);
      xw.w = fmaf(w, xk.w, xw.w);
    };

    // k-steps; each consumes slot k%3 then refills it with stream pos k+3
    { v4f t = xq0; xq0 = pc[192]; step(t, false); }                 // k=0 -> (b,3)
    { v4f t = xq1; xq1 = pc[256]; step(t, false); }                 // k=1 -> (b,4)
    { v4f t = xq2; xq2 = pc[320]; step(t, false); }                 // k=2 -> (b,5)
    { v4f t = xq0; xq0 = pc[384]; step(t, false); }                 // k=3 -> (b,6)
    { v4f t = xq1; xq1 = pc[448]; step(t, false); }                 // k=4 -> (b,7)
    {
      v4f t = xq2;                                                  // k=5 -> (b,8)
      size_t idx = (size_t)b * NV4 + 512 + lane;                    // lanes>=48 spill
      if (idx > LASTV) idx = LASTV;                                 // into next b (masked)
      xq2 = xv[idx];
      step(t, false);
    }
    float u_nxt = u_cur;
    { v4f t = xq0; xq0 = pn[0];   step(t, false); }                 // k=6 -> (bn,0)
    if constexpr (PRECOMP_U)
      u_nxt = u_arr[(size_t)(bn < Bn ? bn : Bn - 1) * 16 + m];
    { v4f t = xq1; xq1 = pn[64];  step(t, false); }                 // k=7 -> (bn,1)
    { v4f t = xq2; xq2 = pn[128]; step(t, true);  }                 // k=8 -> (bn,2)

    // ---- cross-row (g) combine + normalize ----
    s_acc += __shfl_xor(s_acc, 16); s_acc += __shfl_xor(s_acc, 32);
    xw.x += __shfl_xor(xw.x, 16); xw.x += __shfl_xor(xw.x, 32);
    xw.y += __shfl_xor(xw.y, 16); xw.y += __shfl_xor(xw.y, 32);
    xw.z += __shfl_xor(xw.z, 16); xw.z += __shfl_xor(xw.z, 32);
    xw.w += __shfl_xor(xw.w, 16); xw.w += __shfl_xor(xw.w, 32);
    const float rS = __builtin_amdgcn_rcpf(s_acc);   // 1 inst; err ~1e-7 << thresh
    v2f xwlo = { xw.x * rS, xw.y * rS };
    v2f xwhi = { xw.z * rS, xw.w * rS };

    // ---- final matvec via the same butterfly; lane ends with out[lane] ----
    float q[16];
#pragma unroll
    for (int pos = 0; pos < 16; ++pos) {
      v4f Wv = W2[pos][lane];                 // conflict-free ds_read_b128
      v2f t = pk_mul(lo2(Wv), xwlo);
      t = pk_fma(hi2(Wv), xwhi, t);
      q[pos] = t.x + t.y;
    }
    float hp = reduce_scatter16(q) + biasr;
    float res = hp > 0.f ? hp : (__expf(hp) - 1.f);   // elu
    out[(size_t)b * 64 + lane] = res;

    pc = pn;
    u_cur = u_nxt;
  }
}

extern "C" void kernel_launch(void* const* d_in, const int* in_sizes, int n_in,
                              void* d_out, int out_size, void* d_ws, size_t ws_size,
                              hipStream_t stream) {
  const float* x_target = (const float*)d_in[0];
  const float* x_neigh  = (const float*)d_in[1];
  const float* align_w  = (const float*)d_in[2];
  const float* align_b  = (const float*)d_in[3];
  const float* attn1_w  = (const float*)d_in[4];
  const float* attn1_b  = (const float*)d_in[5];
  const float* attn2_w  = (const float*)d_in[6];
  const float* attn2_b  = (const float*)d_in[7];
  float* out = (float*)d_out;

  float* ws = (float*)d_ws;
  float* wsM  = ws;            // 1024 floats
  float* wsMt = ws + 1024;     // 1024 floats
  float* wsKt = ws + 2048;     // 16 floats
  float* u_arr = ws + 2064;    // B*16 floats (4 MB)
  size_t need = (2064 + (size_t)Bn * 16) * sizeof(float);
  bool precomp = ws_size >= need;

  gat_prep<<<4, 256, 0, stream>>>(align_w, align_b, attn1_w, attn1_b, wsM, wsMt, wsKt);

  const int blocks = 2048;
  const int waves_total = blocks * 4;
  if (precomp) {
    gat_u<<<(Bn * 16) / 256, 256, 0, stream>>>(x_target, wsMt, wsKt, u_arr);
    gat_main<true, 4><<<blocks, 256, 0, stream>>>(x_target, x_neigh, align_w, align_b,
                                                  attn2_w, attn2_b, wsM, wsMt, wsKt,
                                                  u_arr, out, waves_total);
  } else {
    gat_main<false, 2><<<blocks, 256, 0, stream>>>(x_target, x_neigh, align_w, align_b,
                                                   attn2_w, attn2_b, wsM, wsMt, wsKt,
                                                   u_arr, out, waves_total);
  }
}